// Round 2
// baseline (409.732 us; speedup 1.0000x reference)
//
#include <hip/hip_runtime.h>
#include <stdint.h>

// ---------------------------------------------------------------------------
// Fused LSTM cell, round 2.
//  prep_w: Wx/Wh (fp32) -> Bt (bf16, 1024 x 384) in d_ws, fragment-ordered,
//          K zero-padded (x: 100->128, h: 256) so main kernel has no guards.
//  lstm_main: gates = [x|h] @ Bt^T (bf16 MFMA 16x16x32) + bias; gate combine
//          lane-local (gate == 16-col fragment index); c/h out fp32.
// Block 512 thr (8 waves = 4 wr x 2 wc), tile 256 rows x 128 gate-cols
// (nt = 32 H-cols x 4 gates). Per-wave 64x64, acc[4][4] f32x4 = 64 regs ->
// <=128 total regs -> 16 waves/CU = 2 blocks/CU (LDS 60 KB dbuf also fits 2).
// ---------------------------------------------------------------------------

typedef short          bf16x8 __attribute__((ext_vector_type(8)));
typedef unsigned short u16x8  __attribute__((ext_vector_type(8)));
typedef float          f32x4  __attribute__((ext_vector_type(4)));

#define HDIM   256
#define INDIM  100
#define NROWS  131072
#define KPAD   40            // ushorts per LDS row (80 B, 4-way-max conflicts)
#define NSTAGE 12            // 12 x BK=32 : 4 x-stages (pad 128) + 8 h-stages
#define AOFF(b) ((b) * 256 * KPAD)
#define BOFF(b) (2 * 256 * KPAD + (b) * 128 * KPAD)

__device__ __forceinline__ float fexp(float x) {
  return __builtin_amdgcn_exp2f(x * 1.44269504088896340736f);
}
__device__ __forceinline__ float frcp(float x) { return __builtin_amdgcn_rcpf(x); }
__device__ __forceinline__ float sigm(float x) { return frcp(1.0f + fexp(-x)); }
__device__ __forceinline__ float tanh_fast(float x) {
  return 1.0f - 2.0f * frcp(1.0f + fexp(2.0f * x));
}
__device__ __forceinline__ unsigned short f2bf_rne(float f) {
  union { float f; uint32_t u; } v; v.f = f;
  return (unsigned short)((v.u + 0x7FFFu + ((v.u >> 16) & 1u)) >> 16);
}
__device__ __forceinline__ unsigned int cvt_pk_bf16(float lo, float hi) {
  unsigned int r;
  asm("v_cvt_pk_bf16_f32 %0, %1, %2" : "=v"(r) : "v"(lo), "v"(hi));
  return r;
}

// ---- prep: Bt[gc][k] bf16, gc = nt*128 + wc*64 + gate*16 + col16 ----------
__global__ void prep_w(const float* __restrict__ Wx, const float* __restrict__ Wh,
                       unsigned short* __restrict__ Bt) {
  const int gc = blockIdx.x;          // 0..1023
  const int k  = threadIdx.x;         // 0..383
  const int nt = gc >> 7, c = gc & 127;
  const int wc = (c >> 6) & 1, g = (c >> 4) & 3, col16 = c & 15;
  const int wcol = g * HDIM + nt * 32 + wc * 16 + col16;   // col in W [*,1024]
  float v = 0.0f;
  if (k < 128) { if (k < INDIM) v = Wx[(size_t)k * 1024 + wcol]; }
  else                          v = Wh[(size_t)(k - 128) * 1024 + wcol];
  Bt[(size_t)gc * 384 + k] = f2bf_rne(v);
}

// ---- main -----------------------------------------------------------------
__global__ __launch_bounds__(512, 4)
void lstm_main(const float* __restrict__ X, const float* __restrict__ Cin,
               const float* __restrict__ Hin,
               const unsigned short* __restrict__ Bt,
               const float* __restrict__ bxp, const float* __restrict__ bhp,
               float* __restrict__ out)
{
  __shared__ unsigned short smem[2 * 256 * KPAD + 2 * 128 * KPAD]; // 60 KiB

  const int tid  = threadIdx.x;
  const int orig = blockIdx.x;                  // 0..4095 (%8==0 -> bijective)
  const int lg   = ((orig & 7) << 9) + (orig >> 3);   // XCD-contiguous chunks
  const int mt   = lg >> 3;                     // M tile 0..511 (256 rows)
  const int nt   = lg & 7;                      // N tile 0..7  (32 H-cols)

  const int lane = tid & 63;
  const int l15  = lane & 15;
  const int kq   = lane >> 4;                   // k-quarter 0..3
  const int wid  = tid >> 6;
  const int wr   = wid >> 1;                    // 0..3: 64-row group
  const int wc   = wid & 1;                     // 0..1: 16-hcol half

  const int ch = nt * 32 + wc * 16 + l15;       // this lane's H column
  float bias[4];
#pragma unroll
  for (int g = 0; g < 4; ++g) bias[g] = bxp[g * HDIM + ch] + bhp[g * HDIM + ch];

  // staging maps: A 256x32 fp32->bf16 (2 thr/row); B 128x32 bf16 direct
  const int arow = tid >> 1;
  const int aks  = (tid & 1) * 16;
  const int bcol = tid >> 2;
  const int bq   = tid & 3;
  const unsigned short* btp = Bt + (size_t)(nt * 128 + bcol) * 384 + bq * 8;

  f32x4 acc[4][4];
#pragma unroll
  for (int m = 0; m < 4; ++m)
#pragma unroll
    for (int g = 0; g < 4; ++g)
#pragma unroll
      for (int e = 0; e < 4; ++e) acc[m][g][e] = 0.0f;

  float av[16];
  u16x8 bw;

  auto stage_load = [&](int s) {
    const bool   xph  = (s < 4);
    const float* Asrc = xph ? X : Hin;
    const int    lda  = xph ? INDIM : HDIM;
    const int    kb   = xph ? s * 32 : (s - 4) * 32;
    const float* ap   = Asrc + (size_t)(mt * 256 + arow) * lda + kb + aks;
#pragma unroll
    for (int j = 0; j < 4; ++j) {
      float4 v = make_float4(0.f, 0.f, 0.f, 0.f);
      if (kb + aks + j * 4 + 4 <= lda) v = *reinterpret_cast<const float4*>(ap + j * 4);
      av[4 * j + 0] = v.x; av[4 * j + 1] = v.y;
      av[4 * j + 2] = v.z; av[4 * j + 3] = v.w;
    }
    bw = *reinterpret_cast<const u16x8*>(btp + s * 32);   // L2-hit, coalesced
  };

  auto stage_write = [&](int b) {
    unsigned int ua[8];
#pragma unroll
    for (int j = 0; j < 8; ++j) ua[j] = cvt_pk_bf16(av[2 * j], av[2 * j + 1]);
    unsigned short* Ad = smem + AOFF(b) + arow * KPAD + aks;
    *reinterpret_cast<uint4*>(Ad)     = *reinterpret_cast<uint4*>(&ua[0]);
    *reinterpret_cast<uint4*>(Ad + 8) = *reinterpret_cast<uint4*>(&ua[4]);
    *reinterpret_cast<u16x8*>(smem + BOFF(b) + bcol * KPAD + bq * 8) = bw;
  };

  // prologue
  stage_load(0);
  stage_write(0);
  __syncthreads();

#pragma unroll
  for (int s = 0; s < NSTAGE; ++s) {
    if (s + 1 < NSTAGE) stage_load(s + 1);      // issue globals early

    const unsigned short* Ab = smem + AOFF(s & 1);
    const unsigned short* Bb = smem + BOFF(s & 1);
    bf16x8 af[4], bf[4];
#pragma unroll
    for (int m = 0; m < 4; ++m)
      af[m] = *reinterpret_cast<const bf16x8*>(
          &Ab[(wr * 64 + m * 16 + l15) * KPAD + kq * 8]);
#pragma unroll
    for (int g = 0; g < 4; ++g)
      bf[g] = *reinterpret_cast<const bf16x8*>(
          &Bb[(wc * 64 + g * 16 + l15) * KPAD + kq * 8]);

    __builtin_amdgcn_s_setprio(1);
#pragma unroll
    for (int m = 0; m < 4; ++m)
#pragma unroll
      for (int g = 0; g < 4; ++g)
        acc[m][g] = __builtin_amdgcn_mfma_f32_16x16x32_bf16(
            af[m], bf[g], acc[m][g], 0, 0, 0);
    __builtin_amdgcn_s_setprio(0);

    if (s + 1 < NSTAGE) stage_write((s + 1) & 1);
    __syncthreads();
  }

  // epilogue: fully lane-local gate combine (D: col=lane&15, row=kq*4+e)
  const size_t HTOT = (size_t)NROWS * HDIM;
#pragma unroll
  for (int m = 0; m < 4; ++m) {
#pragma unroll
    for (int e = 0; e < 4; ++e) {
      const int r = mt * 256 + wr * 64 + m * 16 + kq * 4 + e;
      const float pi = acc[m][0][e] + bias[0];
      const float pf = acc[m][1][e] + bias[1];
      const float pg = acc[m][2][e] + bias[2];
      const float po = acc[m][3][e] + bias[3];
      const float Cv = Cin[(size_t)r * HDIM + ch];
      const float ig = sigm(pi), fg = sigm(pf);
      const float gg = tanh_fast(pg), og = sigm(po);
      const float co = fg * Cv + ig * gg;
      const float ho = og * tanh_fast(co);
      out[(size_t)r * HDIM + ch]        = co;
      out[HTOT + (size_t)r * HDIM + ch] = ho;
    }
  }
}

extern "C" void kernel_launch(void* const* d_in, const int* in_sizes, int n_in,
                              void* d_out, int out_size, void* d_ws, size_t ws_size,
                              hipStream_t stream) {
  const float* x  = (const float*)d_in[0];
  const float* C  = (const float*)d_in[1];
  const float* h  = (const float*)d_in[2];
  const float* Wx = (const float*)d_in[3];
  const float* Wh = (const float*)d_in[4];
  const float* bx = (const float*)d_in[5];
  const float* bh = (const float*)d_in[6];
  float* o = (float*)d_out;
  unsigned short* Bt = (unsigned short*)d_ws;   // 1024*384*2 = 786 KiB

  prep_w<<<dim3(1024), dim3(384), 0, stream>>>(Wx, Wh, Bt);
  lstm_main<<<dim3(4096), dim3(512), 0, stream>>>(x, C, h, Bt, bx, bh, o);
}

// Round 3
// 232.614 us; speedup vs baseline: 1.7614x; 1.7614x over previous
//
#include <hip/hip_runtime.h>
#include <stdint.h>

// ---------------------------------------------------------------------------
// Fused LSTM cell, round 3.
//  prep_w: pack W into fragment-contiguous bf16 blobs in d_ws:
//          Bt[bn(8)][fid(8)][kstep(12)][lane(64)][e(8)], fid = g*2 + wc.
//          One MFMA B-fragment == one coalesced 16B/lane load (L2-resident).
//  lstm_main: 256 thr (4 waves, 2x2), block tile 128 rows x 128 gate-cols,
//          per-wave 64x64. BK=64 -> 6 stages, 1 barrier each. LDS holds A
//          only: dbuf 2 x [128][64] ushort (32 KiB), rows = 128B with XOR
//          chunk swizzle c^=row&7 -> conflict-free reads AND writes.
//          B fragments straight from L2. 3 blocks/CU for implicit overlap.
// ---------------------------------------------------------------------------

typedef short          bf16x8 __attribute__((ext_vector_type(8)));
typedef unsigned short u16x8  __attribute__((ext_vector_type(8)));
typedef float          f32x4  __attribute__((ext_vector_type(4)));

#define HDIM   256
#define INDIM  100
#define NROWS  131072
#define NSTAGE 6              // 6 x BK=64 : 2 x-stages (pad 128) + 4 h-stages

__device__ __forceinline__ float fexp(float x) {
  return __builtin_amdgcn_exp2f(x * 1.44269504088896340736f);
}
__device__ __forceinline__ float frcp(float x) { return __builtin_amdgcn_rcpf(x); }
__device__ __forceinline__ float sigm(float x) { return frcp(1.0f + fexp(-x)); }
__device__ __forceinline__ float tanh_fast(float x) {
  return 1.0f - 2.0f * frcp(1.0f + fexp(2.0f * x));
}
__device__ __forceinline__ unsigned short f2bf_rne(float f) {
  union { float f; uint32_t u; } v; v.f = f;
  return (unsigned short)((v.u + 0x7FFFu + ((v.u >> 16) & 1u)) >> 16);
}
__device__ __forceinline__ unsigned int cvt_pk_bf16(float lo, float hi) {
  unsigned int r;
  asm("v_cvt_pk_bf16_f32 %0, %1, %2" : "=v"(r) : "v"(lo), "v"(hi));
  return r;
}

// ---- prep: one unit = (bn*8+fid)*12 + kstep; 64 lanes x 8 k-elems ---------
__global__ void prep_w(const float* __restrict__ Wx, const float* __restrict__ Wh,
                       unsigned short* __restrict__ Bt) {
  const int unit = blockIdx.x * 4 + (threadIdx.x >> 6);   // 0..767
  const int lane = threadIdx.x & 63;
  const int kst  = unit % 12;
  const int fidb = unit / 12;            // bn*8 + fid
  const int bn   = fidb >> 3, fid = fidb & 7;
  const int g    = fid >> 1,  wc  = fid & 1;
  const int wcol = g * HDIM + bn * 32 + wc * 16 + (lane & 15);
  const int kb   = kst * 32 + (lane >> 4) * 8;
  unsigned short v[8];
#pragma unroll
  for (int e = 0; e < 8; ++e) {
    const int k = kb + e;                // 0..383
    float f = 0.0f;
    if (k < INDIM)       f = Wx[(size_t)k * 1024 + wcol];
    else if (k >= 128)   f = Wh[(size_t)(k - 128) * 1024 + wcol];
    v[e] = f2bf_rne(f);
  }
  *reinterpret_cast<u16x8*>(Bt + (size_t)unit * 512 + lane * 8) =
      *reinterpret_cast<u16x8*>(v);
}

// ---- main -----------------------------------------------------------------
__global__ __launch_bounds__(256, 3)
void lstm_main(const float* __restrict__ X, const float* __restrict__ Cin,
               const float* __restrict__ Hin,
               const unsigned short* __restrict__ Bt,
               const float* __restrict__ bxp, const float* __restrict__ bhp,
               float* __restrict__ out)
{
  __shared__ unsigned short As[2][128 * 64];   // 32 KiB total

  const int tid  = threadIdx.x;
  const int orig = blockIdx.x;                 // 0..8191 (%8==0 -> bijective)
  const int lg   = ((orig & 7) << 10) | (orig >> 3);
  const int mt   = lg >> 3;                    // M tile 0..1023 (128 rows)
  const int bn   = lg & 7;                     // N tile 0..7 (32 H-cols)

  const int lane = tid & 63;
  const int l15  = lane & 15;
  const int kq   = lane >> 4;
  const int wid  = tid >> 6;                   // 0..3
  const int wr   = wid >> 1;                   // 0..1: 64-row group
  const int wc   = wid & 1;                    // 0..1: 16-hcol half

  f32x4 acc[4][4];                             // [m][gate]
#pragma unroll
  for (int m = 0; m < 4; ++m)
#pragma unroll
    for (int g = 0; g < 4; ++g)
#pragma unroll
      for (int e = 0; e < 4; ++e) acc[m][g][e] = 0.0f;

  float av[32];                                // A stage regs (8 float4)

  auto stage_load = [&](int s) {
    const bool   xph = (s < 2);
    const float* Ap  = xph ? X : Hin;
    const int    lda = xph ? INDIM : HDIM;
    const int    kb  = xph ? s * 64 : (s - 2) * 64;
#pragma unroll
    for (int i = 0; i < 4; ++i) {
      const int ci = i * 256 + tid;            // flat 16B-chunk index 0..1023
      const int r  = ci >> 3, c = ci & 7;
      const int k0 = kb + c * 8;
      const float* p = Ap + (size_t)(mt * 128 + r) * lda + k0;
      float4 lo = make_float4(0.f, 0.f, 0.f, 0.f);
      float4 hi = make_float4(0.f, 0.f, 0.f, 0.f);
      if (k0 + 4 <= lda) lo = *reinterpret_cast<const float4*>(p);
      if (k0 + 8 <= lda) hi = *reinterpret_cast<const float4*>(p + 4);
      av[i*8+0]=lo.x; av[i*8+1]=lo.y; av[i*8+2]=lo.z; av[i*8+3]=lo.w;
      av[i*8+4]=hi.x; av[i*8+5]=hi.y; av[i*8+6]=hi.z; av[i*8+7]=hi.w;
    }
  };

  auto stage_write = [&](int b) {
#pragma unroll
    for (int i = 0; i < 4; ++i) {
      const int ci = i * 256 + tid;
      const int r  = ci >> 3, c = ci & 7;
      unsigned int u[4];
#pragma unroll
      for (int j = 0; j < 4; ++j)
        u[j] = cvt_pk_bf16(av[i*8 + 2*j], av[i*8 + 2*j + 1]);
      *reinterpret_cast<uint4*>(&As[b][r * 64 + ((c ^ (r & 7)) * 8)]) =
          *reinterpret_cast<uint4*>(u);
    }
  };

  // prologue
  stage_load(0);
  stage_write(0);
  __syncthreads();

#pragma unroll
  for (int s = 0; s < NSTAGE; ++s) {
    if (s + 1 < NSTAGE) stage_load(s + 1);     // A globals for next stage (T14)

    // B fragments for this stage: 8 coalesced 16B/lane loads from L2
    bf16x8 bfr[2][4];
#pragma unroll
    for (int kk = 0; kk < 2; ++kk)
#pragma unroll
      for (int g = 0; g < 4; ++g) {
        const int fid = g * 2 + wc;
        const size_t off =
            ((size_t)((bn * 8 + fid) * 12 + (s * 2 + kk))) * 512 + lane * 8;
        bfr[kk][g] = *reinterpret_cast<const bf16x8*>(Bt + off);
      }

    const unsigned short* Ab = As[s & 1];
#pragma unroll
    for (int kk = 0; kk < 2; ++kk) {
      bf16x8 afr[4];
#pragma unroll
      for (int m = 0; m < 4; ++m) {
        const int row = wr * 64 + m * 16 + l15;
        afr[m] = *reinterpret_cast<const bf16x8*>(
            &Ab[row * 64 + (((kk * 4 + kq) ^ (row & 7)) * 8)]);
      }
      __builtin_amdgcn_s_setprio(1);
#pragma unroll
      for (int m = 0; m < 4; ++m)
#pragma unroll
        for (int g = 0; g < 4; ++g)
          acc[m][g] = __builtin_amdgcn_mfma_f32_16x16x32_bf16(
              afr[m], bfr[kk][g], acc[m][g], 0, 0, 0);
      __builtin_amdgcn_s_setprio(0);
    }

    if (s + 1 < NSTAGE) stage_write((s + 1) & 1);
    __syncthreads();
  }

  // epilogue: lane-local gate combine (D: col=lane&15, row=kq*4+e)
  const int ch = bn * 32 + wc * 16 + l15;
  float bias[4];
#pragma unroll
  for (int g = 0; g < 4; ++g) bias[g] = bxp[g * HDIM + ch] + bhp[g * HDIM + ch];

  const size_t HTOT = (size_t)NROWS * HDIM;
#pragma unroll
  for (int m = 0; m < 4; ++m) {
#pragma unroll
    for (int e = 0; e < 4; ++e) {
      const int r = mt * 128 + wr * 64 + m * 16 + kq * 4 + e;
      const float pi = acc[m][0][e] + bias[0];
      const float pf = acc[m][1][e] + bias[1];
      const float pg = acc[m][2][e] + bias[2];
      const float po = acc[m][3][e] + bias[3];
      const float Cv = Cin[(size_t)r * HDIM + ch];
      const float ig = sigm(pi), fg = sigm(pf);
      const float gg = tanh_fast(pg), og = sigm(po);
      const float co = fg * Cv + ig * gg;
      const float ho = og * tanh_fast(co);
      out[(size_t)r * HDIM + ch]        = co;
      out[HTOT + (size_t)r * HDIM + ch] = ho;
    }
  }
}

extern "C" void kernel_launch(void* const* d_in, const int* in_sizes, int n_in,
                              void* d_out, int out_size, void* d_ws, size_t ws_size,
                              hipStream_t stream) {
  const float* x  = (const float*)d_in[0];
  const float* C  = (const float*)d_in[1];
  const float* h  = (const float*)d_in[2];
  const float* Wx = (const float*)d_in[3];
  const float* Wh = (const float*)d_in[4];
  const float* bx = (const float*)d_in[5];
  const float* bh = (const float*)d_in[6];
  float* o = (float*)d_out;
  unsigned short* Bt = (unsigned short*)d_ws;   // 768*512*2 = 786 KiB

  prep_w<<<dim3(192), dim3(256), 0, stream>>>(Wx, Wh, Bt);
  lstm_main<<<dim3(8192), dim3(256), 0, stream>>>(x, C, h, Bt, bx, bh, o);
}